// Round 1
// baseline (142.438 us; speedup 1.0000x reference)
//
#include <hip/hip_runtime.h>

// BPMLL loss, B=16384 rows, L=1024 cols.
// Per row: pos = sum_k y_k * exp(-c_k); neg = sum_l (1-y_l) * exp(c_l);
// loss = pos*neg / (sum_y * (L - sum_y));  output = mean over rows.
// Memory-bound: 128 MiB input -> ~21 us floor at 6.3 TB/s.

#define NROWS 16384
#define NCOLS 1024
#define ROWS_PER_BLOCK 4
#define NBLOCKS (NROWS / ROWS_PER_BLOCK)  // 4096

__global__ __launch_bounds__(256) void bpmll_rows_kernel(
    const float* __restrict__ c, const int* __restrict__ y,
    float* __restrict__ partials) {
    const int wave = threadIdx.x >> 6;   // 0..3, one wave per row
    const int lane = threadIdx.x & 63;
    const int row = blockIdx.x * ROWS_PER_BLOCK + wave;

    const float4* __restrict__ c4 = (const float4*)(c + (size_t)row * NCOLS);
    const int4* __restrict__ y4 = (const int4*)(y + (size_t)row * NCOLS);

    float pos = 0.f, neg = 0.f, ycnt = 0.f;
#pragma unroll
    for (int i = 0; i < NCOLS / (64 * 4); ++i) {  // 4 iterations
        float4 cv = c4[lane + 64 * i];   // coalesced 16 B/lane
        int4 yv = y4[lane + 64 * i];
        // one transcendental per element: exp(y ? -c : c), selected into pos/neg
        {
            float t = __expf(yv.x ? -cv.x : cv.x);
            pos += yv.x ? t : 0.f;  neg += yv.x ? 0.f : t;  ycnt += (float)yv.x;
        }
        {
            float t = __expf(yv.y ? -cv.y : cv.y);
            pos += yv.y ? t : 0.f;  neg += yv.y ? 0.f : t;  ycnt += (float)yv.y;
        }
        {
            float t = __expf(yv.z ? -cv.z : cv.z);
            pos += yv.z ? t : 0.f;  neg += yv.z ? 0.f : t;  ycnt += (float)yv.z;
        }
        {
            float t = __expf(yv.w ? -cv.w : cv.w);
            pos += yv.w ? t : 0.f;  neg += yv.w ? 0.f : t;  ycnt += (float)yv.w;
        }
    }

    // wave=64 butterfly reduce (3 values)
#pragma unroll
    for (int off = 32; off > 0; off >>= 1) {
        pos += __shfl_down(pos, off);
        neg += __shfl_down(neg, off);
        ycnt += __shfl_down(ycnt, off);
    }

    __shared__ float acc[ROWS_PER_BLOCK];
    if (lane == 0) {
        const float yn = ycnt;                   // BIAS=(1,1): norms are counts
        const float ybn = (float)NCOLS - ycnt;
        acc[wave] = (pos * neg) / (yn * ybn);
    }
    __syncthreads();
    if (threadIdx.x == 0) {
        partials[blockIdx.x] =
            (acc[0] + acc[1] + acc[2] + acc[3]) * (1.0f / (float)NROWS);
    }
}

__global__ __launch_bounds__(1024) void bpmll_reduce_kernel(
    const float* __restrict__ partials, float* __restrict__ out) {
    float s = 0.f;
#pragma unroll
    for (int i = threadIdx.x; i < NBLOCKS; i += 1024) s += partials[i];
#pragma unroll
    for (int off = 32; off > 0; off >>= 1) s += __shfl_down(s, off);

    __shared__ float smem[16];
    const int lane = threadIdx.x & 63;
    const int wave = threadIdx.x >> 6;
    if (lane == 0) smem[wave] = s;
    __syncthreads();
    if (threadIdx.x == 0) {
        float t = 0.f;
#pragma unroll
        for (int w = 0; w < 16; ++w) t += smem[w];
        out[0] = t;
    }
}

extern "C" void kernel_launch(void* const* d_in, const int* in_sizes, int n_in,
                              void* d_out, int out_size, void* d_ws, size_t ws_size,
                              hipStream_t stream) {
    const float* c = (const float*)d_in[0];
    const int* y = (const int*)d_in[1];
    float* partials = (float*)d_ws;   // NBLOCKS floats = 16 KiB scratch
    float* out = (float*)d_out;

    bpmll_rows_kernel<<<NBLOCKS, 256, 0, stream>>>(c, y, partials);
    bpmll_reduce_kernel<<<1, 1024, 0, stream>>>(partials, out);
}

// Round 2
// 141.437 us; speedup vs baseline: 1.0071x; 1.0071x over previous
//
#include <hip/hip_runtime.h>

// BPMLL loss, B=16384 rows, L=1024 cols, f32 in, scalar f32 out.
// Per row: pos = sum y*exp(-c); neg = sum (1-y)*exp(c);
// loss = pos*neg/(sum_y*(L-sum_y)); out = mean over rows.
// Memory-bound: 128 MiB input. R1 showed 42us @ ~3TB/s effective with
// VGPR=24 (no load hoisting, ~2 outstanding loads/wave) + 4096 short-lived
// blocks. This version: 1024 co-resident blocks, 4 rows/wave, 2 rows per
// iteration with all 16 loads hoisted (explicit register arrays).

#define NROWS 16384
#define NCOLS 1024
#define WPB 4                              // waves per block (256 threads)
#define NBLOCKS 1024                       // 4 blocks/CU x 4 waves = 16 waves/CU, co-resident
#define ROWS_PER_WAVE (NROWS / (NBLOCKS * WPB))  // 4

__device__ __forceinline__ void elem(float cv, int yv,
                                     float& pos, float& neg, float& cnt) {
    float t = __expf(yv ? -cv : cv);   // one transcendental per element
    pos += yv ? t : 0.f;
    neg += yv ? 0.f : t;
    cnt += (float)yv;
}

__global__ __launch_bounds__(256, 4) void bpmll_rows_kernel(
    const float* __restrict__ c, const int* __restrict__ y,
    float* __restrict__ partials) {
    const int wave = threadIdx.x >> 6;
    const int lane = threadIdx.x & 63;
    const int gw = blockIdx.x * WPB + wave;    // global wave id
    const int row0 = gw * ROWS_PER_WAVE;       // 4 contiguous rows per wave

    float wave_loss = 0.f;

#pragma unroll
    for (int it = 0; it < ROWS_PER_WAVE / 2; ++it) {  // 2 iters x 2 rows
        const int rA = row0 + 2 * it;
        const int rB = rA + 1;
        const float4* __restrict__ cA = (const float4*)(c + (size_t)rA * NCOLS);
        const float4* __restrict__ cB = (const float4*)(c + (size_t)rB * NCOLS);
        const int4* __restrict__ yA = (const int4*)(y + (size_t)rA * NCOLS);
        const int4* __restrict__ yB = (const int4*)(y + (size_t)rB * NCOLS);

        // Hoist ALL 16 loads (2 rows x (4 c4 + 4 y4)) -> max MLP per wave.
        float4 ca[4], cb[4];
        int4 ya[4], yb[4];
#pragma unroll
        for (int i = 0; i < 4; ++i) ca[i] = cA[lane + 64 * i];
#pragma unroll
        for (int i = 0; i < 4; ++i) cb[i] = cB[lane + 64 * i];
#pragma unroll
        for (int i = 0; i < 4; ++i) ya[i] = yA[lane + 64 * i];
#pragma unroll
        for (int i = 0; i < 4; ++i) yb[i] = yB[lane + 64 * i];

        float posA = 0.f, negA = 0.f, cntA = 0.f;
        float posB = 0.f, negB = 0.f, cntB = 0.f;
#pragma unroll
        for (int i = 0; i < 4; ++i) {
            elem(ca[i].x, ya[i].x, posA, negA, cntA);
            elem(ca[i].y, ya[i].y, posA, negA, cntA);
            elem(ca[i].z, ya[i].z, posA, negA, cntA);
            elem(ca[i].w, ya[i].w, posA, negA, cntA);
            elem(cb[i].x, yb[i].x, posB, negB, cntB);
            elem(cb[i].y, yb[i].y, posB, negB, cntB);
            elem(cb[i].z, yb[i].z, posB, negB, cntB);
            elem(cb[i].w, yb[i].w, posB, negB, cntB);
        }

        // 64-lane xor-butterfly; 6 independent values pipeline the DS latency.
#pragma unroll
        for (int off = 1; off < 64; off <<= 1) {
            posA += __shfl_xor(posA, off);
            negA += __shfl_xor(negA, off);
            cntA += __shfl_xor(cntA, off);
            posB += __shfl_xor(posB, off);
            negB += __shfl_xor(negB, off);
            cntB += __shfl_xor(cntB, off);
        }
        // All lanes hold full sums; accumulate redundantly (BIAS=(1,1)).
        wave_loss += (posA * negA) / (cntA * ((float)NCOLS - cntA))
                   + (posB * negB) / (cntB * ((float)NCOLS - cntB));
    }

    __shared__ float acc[WPB];
    if (lane == 0) acc[wave] = wave_loss;
    __syncthreads();
    if (threadIdx.x == 0) {
        partials[blockIdx.x] =
            (acc[0] + acc[1] + acc[2] + acc[3]) * (1.0f / (float)NROWS);
    }
}

__global__ __launch_bounds__(256) void bpmll_reduce_kernel(
    const float* __restrict__ partials, float* __restrict__ out) {
    // 1024 partials, 256 threads -> exactly one float4 per thread.
    float4 v = ((const float4*)partials)[threadIdx.x];
    float s = v.x + v.y + v.z + v.w;
#pragma unroll
    for (int off = 1; off < 64; off <<= 1) s += __shfl_xor(s, off);

    __shared__ float smem[4];
    const int lane = threadIdx.x & 63;
    const int wave = threadIdx.x >> 6;
    if (lane == 0) smem[wave] = s;
    __syncthreads();
    if (threadIdx.x == 0) out[0] = smem[0] + smem[1] + smem[2] + smem[3];
}

extern "C" void kernel_launch(void* const* d_in, const int* in_sizes, int n_in,
                              void* d_out, int out_size, void* d_ws, size_t ws_size,
                              hipStream_t stream) {
    const float* c = (const float*)d_in[0];
    const int* y = (const int*)d_in[1];
    float* partials = (float*)d_ws;   // NBLOCKS floats = 4 KiB scratch
    float* out = (float*)d_out;

    bpmll_rows_kernel<<<NBLOCKS, 256, 0, stream>>>(c, y, partials);
    bpmll_reduce_kernel<<<1, 256, 0, stream>>>(partials, out);
}